// Round 4
// baseline (692.917 us; speedup 1.0000x reference)
//
#include <hip/hip_runtime.h>
#include <math.h>

#define DIMN 2048
#define HDIM 256
#define NSIG 6
#define NHEADS 4
#define HEADDIM 64
#define SWHID 4096
#define BB 4
#define SSEQ 2048
#define EPSF 1e-6f
#define NBLK 512
#define NBAR 4

__device__ __forceinline__ float wsum(float v) {
    #pragma unroll
    for (int m = 1; m < 64; m <<= 1) v += __shfl_xor(v, m, 64);
    return v;
}

__device__ __forceinline__ float dot4(float4 a, float4 b) {
    return a.x*b.x + a.y*b.y + a.z*b.z + a.w*b.w;
}

// Agent-scope coherence-point accessors (compile to sc1 loads/stores that
// bypass L1/L2). All cross-block intermediates go through these, so NO
// acquire-invalidate is needed at barriers -> weight lines stay hot in L2.
__device__ __forceinline__ float ldag(const float* p) {
    return __hip_atomic_load((const float*)p, __ATOMIC_RELAXED,
                             __HIP_MEMORY_SCOPE_AGENT);
}
__device__ __forceinline__ void stag(float* p, float v) {
    __hip_atomic_store(p, v, __ATOMIC_RELAXED, __HIP_MEMORY_SCOPE_AGENT);
}

// Zero-RMW barrier. R3's tree still serialized 64 RMWs on the root line
// (~16us/barrier). Here: arrival = one release store to an OWN slot (fully
// parallel); block 0 polls all 512 slots with relaxed sc1 loads (256 thr x 2
// slots); one release store to go; others spin relaxed on go. No acquire:
// intermediates are read via sc1 anyway, and weights are read-only.
__device__ __forceinline__ void gbar(unsigned* sl, unsigned* go) {
    __syncthreads();   // drains each thread's vmcnt -> block's stores visible
    int t = threadIdx.x;
    if (blockIdx.x == 0) {
        if (t == 0) {
            while (__hip_atomic_load(&sl[1], __ATOMIC_RELAXED,
                                     __HIP_MEMORY_SCOPE_AGENT) == 0u)
                __builtin_amdgcn_s_sleep(1);
        } else {
            unsigned a0 = 0u, a1 = 0u;
            while (true) {
                if (!a0) a0 = __hip_atomic_load(&sl[2*t], __ATOMIC_RELAXED,
                                                __HIP_MEMORY_SCOPE_AGENT);
                if (!a1) a1 = __hip_atomic_load(&sl[2*t+1], __ATOMIC_RELAXED,
                                                __HIP_MEMORY_SCOPE_AGENT);
                if (a0 && a1) break;
                __builtin_amdgcn_s_sleep(1);
            }
        }
        __syncthreads();
        if (t == 0)
            __hip_atomic_store(go, 1u, __ATOMIC_RELEASE,
                               __HIP_MEMORY_SCOPE_AGENT);
    } else {
        if (t == 0) {
            __hip_atomic_store(&sl[blockIdx.x], 1u, __ATOMIC_RELEASE,
                               __HIP_MEMORY_SCOPE_AGENT);
            while (__hip_atomic_load(go, __ATOMIC_RELAXED,
                                     __HIP_MEMORY_SCOPE_AGENT) == 0u)
                __builtin_amdgcn_s_sleep(2);
        }
        __syncthreads();
    }
}

struct Params {
    const float *ipw, *ipb, *spw, *spb;
    const float *epi, *ale, *ood, *cunc, *ece, *moral;
    const float *chw1, *chb1, *chw2, *chb2;
    const float *outw, *outb;
    const float *sumw1, *sumb1, *rms1;
    const float *sww1, *sww3, *sww2;
    const float *sumw2, *sumb2, *rms2;
    float *us, *t1n, *h, *t2, *t3n, *accum;
    float *conf, *sig;
    unsigned *slots;   // NBAR * NBLK
    unsigned *go;      // NBAR * 32 (line-spaced flags)
};

__global__ __launch_bounds__(256) void kinit(float* accum, unsigned* slots,
                                             unsigned* go) {
    int t = threadIdx.x;
    if (t < 8) accum[t] = 0.f;
    for (int i = t; i < NBAR * NBLK; i += 256) slots[i] = 0u;
    for (int i = t; i < NBAR * 32; i += 256) go[i] = 0u;
}

// One kernel: block 0 runs the whole front-end (P0) while 511 blocks prefetch
// exactly the weight rows THEY will consume in S3..S6 (right XCD's L2);
// then 4 barrier-separated streaming phases. 512 blocks x 256 thr, 64 KiB
// LDS -> 2 blocks/CU co-resident (proven R2/R3), barrier cannot deadlock.
__global__ __launch_bounds__(256, 2) void kchain(Params p)
{
    __shared__ __align__(16) float smem[16384];   // 64 KiB, reused per phase
    int t = threadIdx.x, wv = t >> 6, lane = t & 63;
    int bid = blockIdx.x;
    int gw = bid * 4 + wv;                        // global wave id 0..2047

    // =============== P0 ===============
    if (bid == 0) {
        float* sA   = smem;          // 768
        float* sC   = smem + 768;    // 768
        float* sSig = smem + 1536;   // 24
        float* sGram= smem + 1568;   // 16
        float* sAtt = smem + 1600;   // 576
        float* sBar = smem + 2176;   // 96
        float* sRedW= smem + 2272;   // 16
        float* sHu  = smem + 2288;   // 16
        float* sHv  = smem + 2304;   // 16
        float* sG   = smem + 2320;   // 1024 [b*256+m]

        // A[r] = ipw[r,:].spw ; C[r] = ipw[r,:].spb + ipb[r], r in [0,768)
        {
            float4 a4 = ((const float4*)p.spw)[lane];
            float4 b4 = ((const float4*)p.spb)[lane];
            for (int r = wv; r < 768; r += 4) {
                float4 w = ((const float4*)(p.ipw + (size_t)r * HDIM))[lane];
                float aa = wsum(dot4(w, a4));
                float cc = wsum(dot4(w, b4));
                if (lane == 0) { sA[r] = aa; sC[r] = cc + p.ipb[r]; }
            }
        }
        // signals: wave wv = batch b
        {
            int b = wv;
            float se = wsum(p.epi[b * 64 + lane]) * (1.f / 64.f);
            float sa = wsum(p.ale[b * 64 + lane]) * (1.f / 64.f);
            if (lane == 0) {
                sSig[b*6+0] = se; sSig[b*6+1] = sa;
                sSig[b*6+2] = p.ood[b]; sSig[b*6+3] = p.cunc[b];
                sSig[b*6+4] = p.ece[0]; sSig[b*6+5] = p.moral[b];
                #pragma unroll
                for (int k = 0; k < NSIG; k++) p.sig[b*6+k] = sSig[b*6+k];
            }
        }
        __syncthreads();
        // per-head Gram scalars: wave wv = head
        {
            int hh = wv;
            float aq = sA[hh*64+lane],     cq = sC[hh*64+lane];
            float ak = sA[256+hh*64+lane], ck = sC[256+hh*64+lane];
            float g0 = wsum(aq*ak), g1 = wsum(aq*ck);
            float g2 = wsum(cq*ak), g3 = wsum(cq*ck);
            if (lane == 0) { sGram[hh*4+0]=g0; sGram[hh*4+1]=g1;
                             sGram[hh*4+2]=g2; sGram[hh*4+3]=g3; }
        }
        // confidence head
        {
            float c1[NSIG];
            #pragma unroll
            for (int j = 0; j < NSIG; j++) c1[j] = p.chw1[t*NSIG+j];
            float cb = p.chb1[t], cw2 = p.chw2[t];
            #pragma unroll
            for (int b = 0; b < BB; b++) {
                float z = cb;
                #pragma unroll
                for (int j = 0; j < NSIG; j++) z += sSig[b*6+j] * c1[j];
                float gg = 0.5f * z * (1.f + erff(z * 0.70710678118654752f));
                float v = wsum(gg * cw2);
                if (lane == 0) sRedW[b*4+wv] = v;
            }
        }
        __syncthreads();
        if (t < BB) {
            float s = sRedW[t*4+0]+sRedW[t*4+1]+sRedW[t*4+2]+sRedW[t*4+3]
                    + p.chb2[0];
            p.conf[t] = 1.f / (1.f + expf(-s));
        }
        // scores + softmax
        if (t < 96) {
            int b = t / 24, r = t % 24, hh = r / 6, qi = r % 6;
            float sq = sSig[b*6+qi];
            float g0=sGram[hh*4+0], g1=sGram[hh*4+1];
            float g2=sGram[hh*4+2], g3=sGram[hh*4+3];
            float sc[NSIG]; float mx = -1e30f;
            #pragma unroll
            for (int ki = 0; ki < NSIG; ki++) {
                float sk = sSig[b*6+ki];
                float s = (g0*sq*sk + g1*sq + g2*sk + g3) * 0.125f;
                sc[ki] = s; mx = fmaxf(mx, s);
            }
            float den = 0;
            #pragma unroll
            for (int ki = 0; ki < NSIG; ki++) { sc[ki] = expf(sc[ki]-mx); den += sc[ki]; }
            float inv = 1.f / den;
            #pragma unroll
            for (int ki = 0; ki < NSIG; ki++)
                sAtt[((b*4+hh)*6+qi)*6+ki] = sc[ki] * inv;
        }
        __syncthreads();
        if (t < 96) {
            int b = t / 24, r = t % 24, hh = r / 6, ki = r % 6;
            float s = 0;
            #pragma unroll
            for (int qi = 0; qi < NSIG; qi++) s += sAtt[((b*4+hh)*6+qi)*6+ki];
            sBar[(b*4+hh)*6+ki] = s * (1.f / 6.f);
        }
        __syncthreads();
        if (t < 16) {
            int b = t >> 2, hh = t & 3;
            float hu = 0, hv = 0;
            #pragma unroll
            for (int ki = 0; ki < NSIG; ki++) {
                float a = sBar[(b*4+hh)*6+ki];
                hu += a * sSig[b*6+ki]; hv += a;
            }
            sHu[b*4+hh] = hu; sHv[b*4+hh] = hv;
        }
        __syncthreads();
        {   // g[b][m] in LDS
            int m = t, hh = m >> 6;
            #pragma unroll
            for (int b = 0; b < BB; b++)
                sG[b*256+m] = sHu[b*4+hh]*sA[512+m] + sHv[b*4+hh]*sC[512+m];
        }
        __syncthreads();
        // us[b][n] = outb[n] + dot(outw[n,:], g[b,:]) -> coherence point
        for (int n = wv; n < HDIM; n += 4) {
            float4 w = ((const float4*)(p.outw + (size_t)n * HDIM))[lane];
            float ob = p.outb[n];
            #pragma unroll
            for (int b = 0; b < BB; b++) {
                float4 g4 = *(const float4*)&sG[b*256 + lane*4];
                float acc = wsum(dot4(w, g4));
                if (lane == 0) stag(&p.us[b*HDIM + n], acc + ob);
            }
        }
    } else {
        // Prefetch exactly this wave's S3..S6 weight rows into our XCD's L2.
        float s = 0.f;
        #pragma unroll
        for (int jj = 0; jj < 2; jj++) {
            int j = bid*8 + wv*2 + jj;
            const float4* r1 = (const float4*)(p.sww1 + (size_t)j * DIMN);
            const float4* r3 = (const float4*)(p.sww3 + (size_t)j * DIMN);
            #pragma unroll
            for (int it = 0; it < 8; it++) {
                float4 v = r1[it*64+lane]; s += v.x+v.y+v.z+v.w;
                float4 u = r3[it*64+lane]; s += u.x+u.y+u.z+u.w;
            }
        }
        {
            const float4* r2 = (const float4*)(p.sww2 + (size_t)gw * SWHID);
            #pragma unroll
            for (int it = 0; it < 16; it++) {
                float4 v = r2[it*64+lane]; s += v.x+v.y+v.z+v.w;
            }
            const float4* rs2 = (const float4*)(p.sumw2 + (size_t)gw * DIMN);
            #pragma unroll
            for (int it = 0; it < 8; it++) {
                float4 v = rs2[it*64+lane]; s += v.x+v.y+v.z+v.w;
            }
            float4 v1 = ((const float4*)(p.sumw1 + (size_t)gw * HDIM))[lane];
            s += v1.x+v1.y+v1.z+v1.w;
        }
        asm volatile("" :: "v"(s));
    }
    gbar(p.slots + 0 * NBLK, p.go + 0 * 32);

    // =============== P1: t1n[b][d], accum[b] ===============
    {
        float* sred = smem + 12288;
        if (t < BB) sred[t] = 0.f;
        __syncthreads();
        int d = gw;
        float4 w = ((const float4*)(p.sumw1 + (size_t)d * HDIM))[lane];
        float acc[BB];
        #pragma unroll
        for (int b = 0; b < BB; b++) {
            float4 u;
            u.x = ldag(&p.us[b*HDIM + lane*4 + 0]);
            u.y = ldag(&p.us[b*HDIM + lane*4 + 1]);
            u.z = ldag(&p.us[b*HDIM + lane*4 + 2]);
            u.w = ldag(&p.us[b*HDIM + lane*4 + 3]);
            acc[b] = dot4(w, u);
        }
        #pragma unroll
        for (int b = 0; b < BB; b++) acc[b] = wsum(acc[b]);
        if (lane == 0) {
            #pragma unroll
            for (int b = 0; b < BB; b++) {
                float v = acc[b] + p.sumb1[d];
                atomicAdd(&sred[b], v * v);
                stag(&p.t1n[b * DIMN + d], v * p.rms1[d]);
            }
        }
        __syncthreads();
        if (t < BB) atomicAdd(&p.accum[t], sred[t]);
    }
    gbar(p.slots + 1 * NBLK, p.go + 1 * 32);

    // =============== P2: SwiGLU (2 rows/wave), batched weight loads ========
    {
        for (int k = 0; k < 32; k++)
            smem[k * 256 + t] = ldag(&p.t1n[k * 256 + t]);
        __syncthreads();
        float s1[BB];
        #pragma unroll
        for (int b = 0; b < BB; b++)
            s1[b] = rsqrtf(ldag(&p.accum[b]) * (1.f / DIMN) + EPSF);
        #pragma unroll
        for (int jj = 0; jj < 2; jj++) {
            int j = bid * 8 + wv * 2 + jj;
            const float4* r1 = (const float4*)(p.sww1 + (size_t)j * DIMN);
            const float4* r3 = (const float4*)(p.sww3 + (size_t)j * DIMN);
            float4 w1v[8], w3v[8];
            #pragma unroll
            for (int it = 0; it < 8; it++) {
                w1v[it] = r1[it * 64 + lane];
                w3v[it] = r3[it * 64 + lane];
            }
            float a1[BB] = {0,0,0,0}, a3[BB] = {0,0,0,0};
            #pragma unroll
            for (int it = 0; it < 8; it++) {
                #pragma unroll
                for (int b = 0; b < BB; b++) {
                    float4 tv = ((const float4*)(smem + b * DIMN))[it * 64 + lane];
                    a1[b] += dot4(w1v[it], tv);
                    a3[b] += dot4(w3v[it], tv);
                }
            }
            #pragma unroll
            for (int b = 0; b < BB; b++) { a1[b] = wsum(a1[b]); a3[b] = wsum(a3[b]); }
            if (lane == 0) {
                #pragma unroll
                for (int b = 0; b < BB; b++) {
                    float a = a1[b] * s1[b];
                    float sil = a / (1.f + expf(-a));
                    stag(&p.h[b * SWHID + j], sil * (a3[b] * s1[b]));
                }
            }
        }
    }
    gbar(p.slots + 2 * NBLK, p.go + 2 * 32);

    // =============== P3: t2[b][d] = h[b] . sw_w2[d,:] ===============
    {
        for (int k = 0; k < 64; k++)
            smem[k * 256 + t] = ldag(&p.h[k * 256 + t]);
        __syncthreads();
        int d = gw;
        const float4* wr = (const float4*)(p.sww2 + (size_t)d * SWHID);
        float4 wv16[16];
        #pragma unroll
        for (int it = 0; it < 16; it++) wv16[it] = wr[it * 64 + lane];
        float acc[BB] = {0,0,0,0};
        #pragma unroll
        for (int it = 0; it < 16; it++) {
            #pragma unroll
            for (int b = 0; b < BB; b++)
                acc[b] += dot4(wv16[it],
                               ((const float4*)(smem + b * SWHID))[it * 64 + lane]);
        }
        #pragma unroll
        for (int b = 0; b < BB; b++) acc[b] = wsum(acc[b]);
        if (lane == 0) {
            #pragma unroll
            for (int b = 0; b < BB; b++) stag(&p.t2[b * DIMN + d], acc[b]);
        }
    }
    gbar(p.slots + 3 * NBLK, p.go + 3 * 32);

    // =============== P4: t3n, accum[4+b] ===============
    {
        float* sred = smem + 12288;
        if (t < BB) sred[t] = 0.f;
        for (int k = 0; k < 32; k++)
            smem[k * 256 + t] = ldag(&p.t2[k * 256 + t]);
        __syncthreads();
        int d = gw;
        const float4* wr = (const float4*)(p.sumw2 + (size_t)d * DIMN);
        float4 wv8[8];
        #pragma unroll
        for (int it = 0; it < 8; it++) wv8[it] = wr[it * 64 + lane];
        float acc[BB] = {0,0,0,0};
        #pragma unroll
        for (int it = 0; it < 8; it++) {
            #pragma unroll
            for (int b = 0; b < BB; b++)
                acc[b] += dot4(wv8[it],
                               ((const float4*)(smem + b * DIMN))[it * 64 + lane]);
        }
        #pragma unroll
        for (int b = 0; b < BB; b++) acc[b] = wsum(acc[b]);
        if (lane == 0) {
            #pragma unroll
            for (int b = 0; b < BB; b++) {
                float v = acc[b] + p.sumb2[d];
                atomicAdd(&sred[b], v * v);
                p.t3n[b * DIMN + d] = v * p.rms2[d];   // k7 reads across kernel boundary
            }
        }
        __syncthreads();
        if (t < BB) atomicAdd(&p.accum[4 + t], sred[t]);
    }
}

// K7: unchanged from baseline (control variable).
__global__ __launch_bounds__(256) void k7_final(
    const float* __restrict__ x, const float* __restrict__ t3n,
    const float* __restrict__ accum, const float* __restrict__ nw,
    float* __restrict__ xa, float* __restrict__ ue)
{
    int t = threadIdx.x, wv = t >> 6, lane = t & 63;
    size_t row = (size_t)blockIdx.x * 4 + wv;
    int b = (int)(row >> 11);  // S = 2048
    float scale2 = rsqrtf(accum[4 + b] * (1.f / DIMN) + EPSF);
    const float4* xr = (const float4*)(x + row * DIMN);
    const float4* tr = (const float4*)(t3n + (size_t)b * DIMN);
    float4 e[8], y[8];
    float ss = 0.f;
    #pragma unroll
    for (int k = 0; k < 8; k++) {
        int idx = k * 64 + lane;
        float4 tv = tr[idx];
        float4 xv = xr[idx];
        e[k].x = tv.x * scale2; e[k].y = tv.y * scale2;
        e[k].z = tv.z * scale2; e[k].w = tv.w * scale2;
        y[k].x = xv.x + 0.05f * e[k].x; y[k].y = xv.y + 0.05f * e[k].y;
        y[k].z = xv.z + 0.05f * e[k].z; y[k].w = xv.w + 0.05f * e[k].w;
        ss += dot4(y[k], y[k]);
    }
    float rs = rsqrtf(wsum(ss) * (1.f / DIMN) + EPSF);
    float4* xo = (float4*)(xa + row * DIMN);
    float4* uo = (float4*)(ue + row * DIMN);
    #pragma unroll
    for (int k = 0; k < 8; k++) {
        int idx = k * 64 + lane;
        float4 nv = ((const float4*)nw)[idx];
        float4 o;
        o.x = y[k].x * rs * nv.x; o.y = y[k].y * rs * nv.y;
        o.z = y[k].z * rs * nv.z; o.w = y[k].w * rs * nv.w;
        xo[idx] = o;
        uo[idx] = e[k];
    }
}

extern "C" void kernel_launch(void* const* d_in, const int* in_sizes, int n_in,
                              void* d_out, int out_size, void* d_ws, size_t ws_size,
                              hipStream_t stream)
{
    (void)in_sizes; (void)n_in; (void)out_size; (void)ws_size;
    const float* x     = (const float*)d_in[0];

    float* out  = (float*)d_out;
    float* xa   = out;                                   // [4,2048,2048]
    float* conf = out + (size_t)BB * SSEQ * DIMN;        // [4]
    float* sig  = conf + BB;                             // [4,6]
    float* ue   = sig + BB * NSIG;                       // [4,2048,2048]

    float* ws = (float*)d_ws;

    Params hp;
    hp.ipw   = (const float*)d_in[9];
    hp.ipb   = (const float*)d_in[10];
    hp.spw   = (const float*)d_in[7];
    hp.spb   = (const float*)d_in[8];
    hp.epi   = (const float*)d_in[1];
    hp.ale   = (const float*)d_in[2];
    hp.ood   = (const float*)d_in[3];
    hp.cunc  = (const float*)d_in[4];
    hp.ece   = (const float*)d_in[5];
    hp.moral = (const float*)d_in[6];
    hp.chw1  = (const float*)d_in[13];
    hp.chb1  = (const float*)d_in[14];
    hp.chw2  = (const float*)d_in[15];
    hp.chb2  = (const float*)d_in[16];
    hp.outw  = (const float*)d_in[11];
    hp.outb  = (const float*)d_in[12];
    hp.sumw1 = (const float*)d_in[17];
    hp.sumb1 = (const float*)d_in[18];
    hp.rms1  = (const float*)d_in[19];
    hp.sww1  = (const float*)d_in[20];
    hp.sww3  = (const float*)d_in[21];
    hp.sww2  = (const float*)d_in[22];
    hp.sumw2 = (const float*)d_in[23];
    hp.sumb2 = (const float*)d_in[24];
    hp.rms2  = (const float*)d_in[25];

    hp.us    = ws;              // 1024
    hp.t1n   = ws + 1024;       // 8192
    hp.h     = ws + 9216;       // 16384
    hp.t2    = ws + 25600;      // 8192
    hp.t3n   = ws + 33792;      // 8192
    hp.accum = ws + 41984;      // 8 (+pad to 32)
    hp.slots = (unsigned*)(ws + 42016);          // NBAR*NBLK = 2048
    hp.go    = (unsigned*)(ws + 42016 + 2048);   // NBAR*32 = 128
    hp.conf  = conf;
    hp.sig   = sig;

    kinit<<<1, 256, 0, stream>>>(hp.accum, hp.slots, hp.go);
    kchain<<<NBLK, 256, 0, stream>>>(hp);
    k7_final<<<2048, 256, 0, stream>>>(x, hp.t3n, hp.accum,
                                       (const float*)d_in[26], xa, ue);
}

// Round 6
// 444.376 us; speedup vs baseline: 1.5593x; 1.5593x over previous
//
#include <hip/hip_runtime.h>
#include <math.h>

#define DIMN 2048
#define HDIM 256
#define NSIG 6
#define NHEADS 4
#define HEADDIM 64
#define SWHID 4096
#define BB 4
#define SSEQ 2048
#define EPSF 1e-6f
#define NBLK 512
#define NBAR 5

__device__ __forceinline__ float wsum(float v) {
    #pragma unroll
    for (int m = 1; m < 64; m <<= 1) v += __shfl_xor(v, m, 64);
    return v;
}

__device__ __forceinline__ float dot4(float4 a, float4 b) {
    return a.x*b.x + a.y*b.y + a.z*b.z + a.w*b.w;
}

// Zero-RMW barrier with R3's (proven) visibility semantics.
//  arrival : ONE release store to an own slot (release emits the agent-scope
//            L2 writeback of all this block's prior normal stores -> data at
//            coherence point). Fully parallel, no RMW serialization anywhere.
//  wake    : block 0's 256 threads poll the 512 slots with relaxed loads
//            (no invalidates), then one release store to go.
//  exit    : t0 does ONE acquire load (L1/L2 invalidate) + __syncthreads ->
//            whole block's subsequent normal loads read fresh data.
// R2/R3 validated the release->flag->acquire transitive chain; R4 validated
// the slot/poll arrival. This combines them.
__device__ __forceinline__ void gbar(unsigned* sl, unsigned* go) {
    __syncthreads();
    int t = threadIdx.x;
    if (blockIdx.x == 0) {
        if (t == 0) {
            while (__hip_atomic_load(&sl[1], __ATOMIC_RELAXED,
                                     __HIP_MEMORY_SCOPE_AGENT) == 0u)
                __builtin_amdgcn_s_sleep(1);
        } else {
            unsigned a0 = 0u, a1 = 0u;
            for (;;) {
                if (!a0) a0 = __hip_atomic_load(&sl[2*t], __ATOMIC_RELAXED,
                                                __HIP_MEMORY_SCOPE_AGENT);
                if (!a1) a1 = __hip_atomic_load(&sl[2*t+1], __ATOMIC_RELAXED,
                                                __HIP_MEMORY_SCOPE_AGENT);
                if (a0 && a1) break;
                __builtin_amdgcn_s_sleep(1);
            }
        }
        __syncthreads();
        if (t == 0) {
            __hip_atomic_store(go, 1u, __ATOMIC_RELEASE,
                               __HIP_MEMORY_SCOPE_AGENT);
            (void)__hip_atomic_load(go, __ATOMIC_ACQUIRE,
                                    __HIP_MEMORY_SCOPE_AGENT);
        }
        __syncthreads();
    } else {
        if (t == 0) {
            __hip_atomic_store(&sl[blockIdx.x], 1u, __ATOMIC_RELEASE,
                               __HIP_MEMORY_SCOPE_AGENT);
            while (__hip_atomic_load(go, __ATOMIC_RELAXED,
                                     __HIP_MEMORY_SCOPE_AGENT) == 0u)
                __builtin_amdgcn_s_sleep(2);
            (void)__hip_atomic_load(go, __ATOMIC_ACQUIRE,
                                    __HIP_MEMORY_SCOPE_AGENT);
        }
        __syncthreads();
    }
}

struct Params {
    const float *ipw, *ipb, *spw, *spb;
    const float *epi, *ale, *ood, *cunc, *ece, *moral;
    const float *chw1, *chb1, *chw2, *chb2;
    const float *outw, *outb;
    const float *sumw1, *sumb1, *rms1;
    const float *sww1, *sww3, *sww2;
    const float *sumw2, *sumb2, *rms2;
    float *A, *C, *us, *t1n, *h, *t2, *t3n, *accum;
    float *conf, *sig;
    unsigned *slots;   // NBAR * NBLK
    unsigned *go;      // NBAR * 32
};

__global__ __launch_bounds__(256) void kinit(float* accum, unsigned* slots,
                                             unsigned* go) {
    int t = threadIdx.x;
    if (t < 8) accum[t] = 0.f;
    for (int i = t; i < NBAR * NBLK; i += 256) slots[i] = 0u;
    for (int i = t; i < NBAR * 32; i += 256) go[i] = 0u;
}

// Prefetch exactly the weight rows block b will consume in P1..P4 (so they
// land in the CONSUMER's XCD L2 when b == own block). asm keeps loads live.
__device__ __forceinline__ void pf_block(const Params& p, int b, int wv,
                                         int lane) {
    float s = 0.f;
    int gw2 = b * 4 + wv;
    #pragma unroll
    for (int jj = 0; jj < 2; jj++) {
        int j = b * 8 + wv * 2 + jj;
        const float4* r1 = (const float4*)(p.sww1 + (size_t)j * DIMN);
        const float4* r3 = (const float4*)(p.sww3 + (size_t)j * DIMN);
        #pragma unroll
        for (int it = 0; it < 8; it++) {
            float4 v = r1[it*64+lane]; s += v.x+v.y+v.z+v.w;
            float4 u = r3[it*64+lane]; s += u.x+u.y+u.z+u.w;
        }
    }
    const float4* r2 = (const float4*)(p.sww2 + (size_t)gw2 * SWHID);
    #pragma unroll
    for (int it = 0; it < 16; it++) { float4 v = r2[it*64+lane]; s += v.x+v.y+v.z+v.w; }
    const float4* rs2 = (const float4*)(p.sumw2 + (size_t)gw2 * DIMN);
    #pragma unroll
    for (int it = 0; it < 8; it++) { float4 v = rs2[it*64+lane]; s += v.x+v.y+v.z+v.w; }
    float4 v1 = ((const float4*)(p.sumw1 + (size_t)gw2 * HDIM))[lane];
    s += v1.x+v1.y+v1.z+v1.w;
    asm volatile("" :: "v"(s));
}

// 512 blocks x 256 threads, 64 KiB LDS -> 2 blocks/CU co-resident (proven
// R2-R4); barrier cannot deadlock. All intermediates use normal cached
// vectorized loads/stores (R3 semantics); visibility via gbar.
__global__ __launch_bounds__(256, 2) void kchain(Params p)
{
    __shared__ __align__(16) float smem[16384];   // 64 KiB, reused per phase
    int t = threadIdx.x, wv = t >> 6, lane = t & 63;
    int bid = blockIdx.x;
    int gw = bid * 4 + wv;                        // global wave id 0..2047

    // =============== S0: A/C (768 waves) || own-row prefetch ===============
    if (gw < 768) {
        int r = gw;
        float4 w  = ((const float4*)(p.ipw + (size_t)r * HDIM))[lane];
        float4 a4 = ((const float4*)p.spw)[lane];
        float4 b4 = ((const float4*)p.spb)[lane];
        float aa = wsum(dot4(w, a4));
        float cc = wsum(dot4(w, b4));
        if (lane == 0) { p.A[r] = aa; p.C[r] = cc + p.ipb[r]; }
    } else {
        pf_block(p, bid, wv, lane);               // blocks 192..511
    }
    gbar(p.slots + 0 * NBLK, p.go + 0 * 32);

    // ====== S1: blocks 0..63 redundant front-end + 4 us rows each;
    //        blocks 64..191 own-row prefetch (were busy in S0);
    //        blocks 256..319 prefetch rows of blocks 0..63 (L3 warm). ======
    if (bid < 64) {
        float* sA   = smem;          // 768
        float* sC   = smem + 768;    // 768
        float* sSig = smem + 1536;   // 24
        float* sGram= smem + 1568;   // 16
        float* sAtt = smem + 1600;   // 576
        float* sBar = smem + 2176;   // 96
        float* sRedW= smem + 2272;   // 16
        float* sHu  = smem + 2288;   // 16
        float* sHv  = smem + 2304;   // 16
        float* sG   = smem + 2320;   // 1024 [b*256+m]

        for (int r = t; r < 768; r += 256) { sA[r] = p.A[r]; sC[r] = p.C[r]; }
        {   // signals: wave wv = batch b
            int b = wv;
            float se = wsum(p.epi[b * 64 + lane]) * (1.f / 64.f);
            float sa = wsum(p.ale[b * 64 + lane]) * (1.f / 64.f);
            if (lane == 0) {
                sSig[b*6+0] = se; sSig[b*6+1] = sa;
                sSig[b*6+2] = p.ood[b]; sSig[b*6+3] = p.cunc[b];
                sSig[b*6+4] = p.ece[0]; sSig[b*6+5] = p.moral[b];
                if (bid == 0) {
                    #pragma unroll
                    for (int k = 0; k < NSIG; k++) p.sig[b*6+k] = sSig[b*6+k];
                }
            }
        }
        __syncthreads();
        {   // per-head Gram scalars: wave wv = head
            int hh = wv;
            float aq = sA[hh*64+lane],     cq = sC[hh*64+lane];
            float ak = sA[256+hh*64+lane], ck = sC[256+hh*64+lane];
            float g0 = wsum(aq*ak), g1 = wsum(aq*ck);
            float g2 = wsum(cq*ak), g3 = wsum(cq*ck);
            if (lane == 0) { sGram[hh*4+0]=g0; sGram[hh*4+1]=g1;
                             sGram[hh*4+2]=g2; sGram[hh*4+3]=g3; }
        }
        if (bid == 0) {   // confidence head: only block 0
            float c1[NSIG];
            #pragma unroll
            for (int j = 0; j < NSIG; j++) c1[j] = p.chw1[t*NSIG+j];
            float cb = p.chb1[t], cw2 = p.chw2[t];
            #pragma unroll
            for (int b = 0; b < BB; b++) {
                float z = cb;
                #pragma unroll
                for (int j = 0; j < NSIG; j++) z += sSig[b*6+j] * c1[j];
                float gg = 0.5f * z * (1.f + erff(z * 0.70710678118654752f));
                float v = wsum(gg * cw2);
                if (lane == 0) sRedW[b*4+wv] = v;
            }
            __syncthreads();
            if (t < BB) {
                float s = sRedW[t*4+0]+sRedW[t*4+1]+sRedW[t*4+2]+sRedW[t*4+3]
                        + p.chb2[0];
                p.conf[t] = 1.f / (1.f + expf(-s));
            }
        } else {
            __syncthreads();
        }
        if (t < 96) {   // scores + softmax
            int b = t / 24, r = t % 24, hh = r / 6, qi = r % 6;
            float sq = sSig[b*6+qi];
            float g0=sGram[hh*4+0], g1=sGram[hh*4+1];
            float g2=sGram[hh*4+2], g3=sGram[hh*4+3];
            float sc[NSIG]; float mx = -1e30f;
            #pragma unroll
            for (int ki = 0; ki < NSIG; ki++) {
                float sk = sSig[b*6+ki];
                float s = (g0*sq*sk + g1*sq + g2*sk + g3) * 0.125f;
                sc[ki] = s; mx = fmaxf(mx, s);
            }
            float den = 0;
            #pragma unroll
            for (int ki = 0; ki < NSIG; ki++) { sc[ki] = expf(sc[ki]-mx); den += sc[ki]; }
            float inv = 1.f / den;
            #pragma unroll
            for (int ki = 0; ki < NSIG; ki++)
                sAtt[((b*4+hh)*6+qi)*6+ki] = sc[ki] * inv;
        }
        __syncthreads();
        if (t < 96) {   // aBar = column mean
            int b = t / 24, r = t % 24, hh = r / 6, ki = r % 6;
            float s = 0;
            #pragma unroll
            for (int qi = 0; qi < NSIG; qi++) s += sAtt[((b*4+hh)*6+qi)*6+ki];
            sBar[(b*4+hh)*6+ki] = s * (1.f / 6.f);
        }
        __syncthreads();
        if (t < 16) {
            int b = t >> 2, hh = t & 3;
            float hu = 0, hv = 0;
            #pragma unroll
            for (int ki = 0; ki < NSIG; ki++) {
                float a = sBar[(b*4+hh)*6+ki];
                hu += a * sSig[b*6+ki]; hv += a;
            }
            sHu[b*4+hh] = hu; sHv[b*4+hh] = hv;
        }
        __syncthreads();
        {   // g[b][m]
            int m = t, hh = m >> 6;
            #pragma unroll
            for (int b = 0; b < BB; b++)
                sG[b*256+m] = sHu[b*4+hh]*sA[512+m] + sHv[b*4+hh]*sC[512+m];
        }
        __syncthreads();
        {   // us row n = bid*4 + wv (one row per wave)
            int n = bid * 4 + wv;
            float4 w = ((const float4*)(p.outw + (size_t)n * HDIM))[lane];
            float ob = p.outb[n];
            #pragma unroll
            for (int b = 0; b < BB; b++) {
                float4 g4 = *(const float4*)&sG[b*256 + lane*4];
                float acc = wsum(dot4(w, g4));
                if (lane == 0) p.us[b*HDIM + n] = acc + ob;
            }
        }
    } else if (bid < 192) {
        pf_block(p, bid, wv, lane);               // own rows (busy in S0)
    } else if (bid >= 256 && bid < 320) {
        pf_block(p, bid - 256, wv, lane);         // rows of blocks 0..63
    }
    gbar(p.slots + 1 * NBLK, p.go + 1 * 32);

    // =============== P1: t1n[b][d], accum[b] ===============
    {
        float* sred = smem + 12288;
        if (t < BB) sred[t] = 0.f;
        __syncthreads();
        int d = gw;
        float4 w = ((const float4*)(p.sumw1 + (size_t)d * HDIM))[lane];
        float acc[BB];
        #pragma unroll
        for (int b = 0; b < BB; b++)
            acc[b] = dot4(w, ((const float4*)(p.us + b * HDIM))[lane]);
        #pragma unroll
        for (int b = 0; b < BB; b++) acc[b] = wsum(acc[b]);
        if (lane == 0) {
            #pragma unroll
            for (int b = 0; b < BB; b++) {
                float v = acc[b] + p.sumb1[d];
                atomicAdd(&sred[b], v * v);
                p.t1n[b * DIMN + d] = v * p.rms1[d];
            }
        }
        __syncthreads();
        if (t < BB) atomicAdd(&p.accum[t], sred[t]);
    }
    gbar(p.slots + 2 * NBLK, p.go + 2 * 32);

    // =============== P2: SwiGLU (2 rows/wave) ===============
    {
        #pragma unroll
        for (int k = 0; k < 8; k++)
            ((float4*)smem)[k * 256 + t] = ((const float4*)p.t1n)[k * 256 + t];
        __syncthreads();
        float s1[BB];
        #pragma unroll
        for (int b = 0; b < BB; b++)
            s1[b] = rsqrtf(p.accum[b] * (1.f / DIMN) + EPSF);
        #pragma unroll
        for (int jj = 0; jj < 2; jj++) {
            int j = bid * 8 + wv * 2 + jj;
            const float4* r1 = (const float4*)(p.sww1 + (size_t)j * DIMN);
            const float4* r3 = (const float4*)(p.sww3 + (size_t)j * DIMN);
            float4 w1v[8], w3v[8];
            #pragma unroll
            for (int it = 0; it < 8; it++) {
                w1v[it] = r1[it * 64 + lane];
                w3v[it] = r3[it * 64 + lane];
            }
            float a1[BB] = {0,0,0,0}, a3[BB] = {0,0,0,0};
            #pragma unroll
            for (int it = 0; it < 8; it++) {
                #pragma unroll
                for (int b = 0; b < BB; b++) {
                    float4 tv = ((const float4*)(smem + b * DIMN))[it * 64 + lane];
                    a1[b] += dot4(w1v[it], tv);
                    a3[b] += dot4(w3v[it], tv);
                }
            }
            #pragma unroll
            for (int b = 0; b < BB; b++) { a1[b] = wsum(a1[b]); a3[b] = wsum(a3[b]); }
            if (lane == 0) {
                #pragma unroll
                for (int b = 0; b < BB; b++) {
                    float a = a1[b] * s1[b];
                    float sil = a / (1.f + expf(-a));
                    p.h[b * SWHID + j] = sil * (a3[b] * s1[b]);
                }
            }
        }
    }
    gbar(p.slots + 3 * NBLK, p.go + 3 * 32);

    // =============== P3: t2[b][d] = h[b] . sw_w2[d,:] ===============
    {
        #pragma unroll
        for (int k = 0; k < 16; k++)
            ((float4*)smem)[k * 256 + t] = ((const float4*)p.h)[k * 256 + t];
        __syncthreads();
        int d = gw;
        const float4* wr = (const float4*)(p.sww2 + (size_t)d * SWHID);
        float4 wv16[16];
        #pragma unroll
        for (int it = 0; it < 16; it++) wv16[it] = wr[it * 64 + lane];
        float acc[BB] = {0,0,0,0};
        #pragma unroll
        for (int it = 0; it < 16; it++) {
            #pragma unroll
            for (int b = 0; b < BB; b++)
                acc[b] += dot4(wv16[it],
                               ((const float4*)(smem + b * SWHID))[it * 64 + lane]);
        }
        #pragma unroll
        for (int b = 0; b < BB; b++) acc[b] = wsum(acc[b]);
        if (lane == 0) {
            #pragma unroll
            for (int b = 0; b < BB; b++) p.t2[b * DIMN + d] = acc[b];
        }
    }
    gbar(p.slots + 4 * NBLK, p.go + 4 * 32);

    // =============== P4: t3n, accum[4+b] ===============
    {
        float* sred = smem + 12288;
        if (t < BB) sred[t] = 0.f;
        #pragma unroll
        for (int k = 0; k < 8; k++)
            ((float4*)smem)[k * 256 + t] = ((const float4*)p.t2)[k * 256 + t];
        __syncthreads();
        int d = gw;
        const float4* wr = (const float4*)(p.sumw2 + (size_t)d * DIMN);
        float4 wv8[8];
        #pragma unroll
        for (int it = 0; it < 8; it++) wv8[it] = wr[it * 64 + lane];
        float acc[BB] = {0,0,0,0};
        #pragma unroll
        for (int it = 0; it < 8; it++) {
            #pragma unroll
            for (int b = 0; b < BB; b++)
                acc[b] += dot4(wv8[it],
                               ((const float4*)(smem + b * DIMN))[it * 64 + lane]);
        }
        #pragma unroll
        for (int b = 0; b < BB; b++) acc[b] = wsum(acc[b]);
        if (lane == 0) {
            #pragma unroll
            for (int b = 0; b < BB; b++) {
                float v = acc[b] + p.sumb2[d];
                atomicAdd(&sred[b], v * v);
                p.t3n[b * DIMN + d] = v * p.rms2[d];   // k7 reads across kernel boundary
            }
        }
        __syncthreads();
        if (t < BB) atomicAdd(&p.accum[4 + t], sred[t]);
    }
}

// K7: unchanged from baseline (control variable).
__global__ __launch_bounds__(256) void k7_final(
    const float* __restrict__ x, const float* __restrict__ t3n,
    const float* __restrict__ accum, const float* __restrict__ nw,
    float* __restrict__ xa, float* __restrict__ ue)
{
    int t = threadIdx.x, wv = t >> 6, lane = t & 63;
    size_t row = (size_t)blockIdx.x * 4 + wv;
    int b = (int)(row >> 11);  // S = 2048
    float scale2 = rsqrtf(accum[4 + b] * (1.f / DIMN) + EPSF);
    const float4* xr = (const float4*)(x + row * DIMN);
    const float4* tr = (const float4*)(t3n + (size_t)b * DIMN);
    float4 e[8], y[8];
    float ss = 0.f;
    #pragma unroll
    for (int k = 0; k < 8; k++) {
        int idx = k * 64 + lane;
        float4 tv = tr[idx];
        float4 xv = xr[idx];
        e[k].x = tv.x * scale2; e[k].y = tv.y * scale2;
        e[k].z = tv.z * scale2; e[k].w = tv.w * scale2;
        y[k].x = xv.x + 0.05f * e[k].x; y[k].y = xv.y + 0.05f * e[k].y;
        y[k].z = xv.z + 0.05f * e[k].z; y[k].w = xv.w + 0.05f * e[k].w;
        ss += dot4(y[k], y[k]);
    }
    float rs = rsqrtf(wsum(ss) * (1.f / DIMN) + EPSF);
    float4* xo = (float4*)(xa + row * DIMN);
    float4* uo = (float4*)(ue + row * DIMN);
    #pragma unroll
    for (int k = 0; k < 8; k++) {
        int idx = k * 64 + lane;
        float4 nv = ((const float4*)nw)[idx];
        float4 o;
        o.x = y[k].x * rs * nv.x; o.y = y[k].y * rs * nv.y;
        o.z = y[k].z * rs * nv.z; o.w = y[k].w * rs * nv.w;
        xo[idx] = o;
        uo[idx] = e[k];
    }
}

extern "C" void kernel_launch(void* const* d_in, const int* in_sizes, int n_in,
                              void* d_out, int out_size, void* d_ws, size_t ws_size,
                              hipStream_t stream)
{
    (void)in_sizes; (void)n_in; (void)out_size; (void)ws_size;
    const float* x     = (const float*)d_in[0];

    float* out  = (float*)d_out;
    float* xa   = out;                                   // [4,2048,2048]
    float* conf = out + (size_t)BB * SSEQ * DIMN;        // [4]
    float* sig  = conf + BB;                             // [4,6]
    float* ue   = sig + BB * NSIG;                       // [4,2048,2048]

    float* ws = (float*)d_ws;

    Params hp;
    hp.ipw   = (const float*)d_in[9];
    hp.ipb   = (const float*)d_in[10];
    hp.spw   = (const float*)d_in[7];
    hp.spb   = (const float*)d_in[8];
    hp.epi   = (const float*)d_in[1];
    hp.ale   = (const float*)d_in[2];
    hp.ood   = (const float*)d_in[3];
    hp.cunc  = (const float*)d_in[4];
    hp.ece   = (const float*)d_in[5];
    hp.moral = (const float*)d_in[6];
    hp.chw1  = (const float*)d_in[13];
    hp.chb1  = (const float*)d_in[14];
    hp.chw2  = (const float*)d_in[15];
    hp.chb2  = (const float*)d_in[16];
    hp.outw  = (const float*)d_in[11];
    hp.outb  = (const float*)d_in[12];
    hp.sumw1 = (const float*)d_in[17];
    hp.sumb1 = (const float*)d_in[18];
    hp.rms1  = (const float*)d_in[19];
    hp.sww1  = (const float*)d_in[20];
    hp.sww3  = (const float*)d_in[21];
    hp.sww2  = (const float*)d_in[22];
    hp.sumw2 = (const float*)d_in[23];
    hp.sumb2 = (const float*)d_in[24];
    hp.rms2  = (const float*)d_in[25];

    hp.A     = ws;              // 768
    hp.C     = ws + 768;        // 768
    hp.us    = ws + 1536;       // 1024
    hp.t1n   = ws + 2560;       // 8192
    hp.h     = ws + 10752;      // 16384
    hp.t2    = ws + 27136;      // 8192
    hp.t3n   = ws + 35328;      // 8192
    hp.accum = ws + 43520;      // 8 (+pad)
    hp.slots = (unsigned*)(ws + 43552);          // NBAR*NBLK = 2560
    hp.go    = (unsigned*)(ws + 43552 + 2560);   // NBAR*32 = 160
    hp.conf  = conf;
    hp.sig   = sig;

    kinit<<<1, 256, 0, stream>>>(hp.accum, hp.slots, hp.go);
    kchain<<<NBLK, 256, 0, stream>>>(hp);
    k7_final<<<2048, 256, 0, stream>>>(x, hp.t3n, hp.accum,
                                       (const float*)d_in[26], xa, ue);
}